// Round 8
// baseline (102.354 us; speedup 1.0000x reference)
//
#include <hip/hip_runtime.h>
#include <math.h>

// GAT layer: N=50000 nodes, E=800000 edges, D_IN=D_OUT=128, H=4, D_H=32
//
// 5-dispatch pipeline:
//   k_setup  : pack W / out_w into bf16 MFMA B-fragments + zero gcnt/gcur
//   k_gemm1b : Wx(bf16) = x @ W via MFMA + fused attention scores s_i/s_j;
//              trailing blocks do the dst-bucket histogram (bucket = dst>>8)
//   k_bin1   : block-local counting sort -> bucket-contiguous tmp
//   k_bin2   : one block per bucket: node counts + scan (emits offs/cnts) +
//              placement; ALSO computes per-edge softmax numerators
//              pexp[e][h] = exp(lrelu(s_i[src]+s_j[dst])) (s_j tile in LDS)
//   k_aggm   : 4 waves/block, 4 consecutive nodes per wave. Staging is now
//              two coalesced loads (csr + pexp) -> LDS; boundary-walking
//              sequential gather accumulates bf16 Wx rows; finalize divides
//              by the running exp-sum. Phase 2: output GEMM + bias + ELU.

typedef __attribute__((ext_vector_type(8))) short short8;
typedef __attribute__((ext_vector_type(4))) float f32x4;

#define BIN_VPT 16          // edges per thread; 4096 edges per 256-thread block

__device__ __forceinline__ float lrelu(float v) { return v >= 0.f ? v : 0.2f * v; }

__device__ __forceinline__ unsigned short f2bf(float f) {  // RNE f32 -> bf16
  unsigned int u = __float_as_uint(f);
  u += 0x7FFFu + ((u >> 16) & 1u);
  return (unsigned short)(u >> 16);
}
// HW packed RNE convert: dst = bf16(lo) | bf16(hi)<<16
__device__ __forceinline__ unsigned int cvt_pk_bf16(float lo, float hi) {
  unsigned int r;
  asm("v_cvt_pk_bf16_f32 %0, %1, %2" : "=v"(r) : "v"(lo), "v"(hi));
  return r;
}
__device__ __forceinline__ float bflo(unsigned int w) { return __uint_as_float(w << 16); }
__device__ __forceinline__ float bfhi(unsigned int w) { return __uint_as_float(w & 0xFFFF0000u); }

// 256-thread exclusive scan helper (value v per thread -> returns excl; ws[4] LDS)
__device__ __forceinline__ int blk_excl_scan(int v, int* ws) {
  const int t = threadIdx.x, lane = t & 63, wv = t >> 6;
  int incl = v;
#pragma unroll
  for (int m = 1; m < 64; m <<= 1) {
    int x = __shfl_up(incl, m, 64);
    if (lane >= m) incl += x;
  }
  if (lane == 63) ws[wv] = incl;
  __syncthreads();
  int woff = 0;
  for (int p = 0; p < wv; ++p) woff += ws[p];
  return woff + incl - v;
}

// ---------------------------------------------------------------- setup
__global__ void k_setup(const float* __restrict__ W, const float* __restrict__ ow,
                        unsigned short* __restrict__ wf, unsigned short* __restrict__ owf,
                        int* __restrict__ gcnt, int* __restrict__ gcur) {
  const int t = blockIdx.x * 256 + threadIdx.x;
  if (blockIdx.x == 0) gcnt[threadIdx.x] = 0;
  if (blockIdx.x == 1) gcur[threadIdx.x] = 0;
  const int which = t >> 11;           // 0: W, 1: out_w
  const int tt = t & 2047;
  const float* M = which ? ow : W;
  unsigned short* F = which ? owf : wf;
  const int lane = tt & 63;
  const int nt = (tt >> 6) & 7;
  const int ks = tt >> 9;
  const int k0 = ks * 32 + (lane >> 4) * 8;
  const int col = nt * 16 + (lane & 15);
  short8 v;
#pragma unroll
  for (int j = 0; j < 8; ++j) v[j] = (short)f2bf(M[(k0 + j) * 128 + col]);
  *(short8*)(F + (size_t)tt * 8) = v;
}

// ---------------------------------------------------------------- GEMM1 + hist
__global__ void k_gemm1b(const float* __restrict__ x, const unsigned short* __restrict__ wf,
                         const float* __restrict__ attn, unsigned int* __restrict__ Wxb,
                         float* __restrict__ s_i, float* __restrict__ s_j, int n,
                         const int* __restrict__ dst, int* __restrict__ gcnt, int E,
                         int gemmBlocks) {
  __shared__ int lc[256];
  if (blockIdx.x >= gemmBlocks) {  // ---- histogram part
    const int bb = blockIdx.x - gemmBlocks;
    lc[threadIdx.x] = 0;
    __syncthreads();
    const int base = bb * (256 * BIN_VPT);
#pragma unroll
    for (int j = 0; j < BIN_VPT; ++j) {
      int e = base + j * 256 + threadIdx.x;
      if (e < E) atomicAdd(&lc[((unsigned int)dst[e]) >> 8], 1);
    }
    __syncthreads();
    int c = lc[threadIdx.x];
    if (c) atomicAdd(&gcnt[threadIdx.x], c);
    return;
  }

  // ---- GEMM part: one wave = 16-row strip, acc[nt] covers cols nt*16..+15
  const int lane = threadIdx.x & 63;
  const int gw = blockIdx.x * (blockDim.x >> 6) + (threadIdx.x >> 6);
  const int r0 = gw * 16;
  if (r0 >= n) return;
  const int g = lane >> 4, c = lane & 15;

  f32x4 acc[8];
#pragma unroll
  for (int nt = 0; nt < 8; ++nt) acc[nt] = (f32x4){0.f, 0.f, 0.f, 0.f};

  const int arow = min(r0 + c, n - 1);
#pragma unroll
  for (int ks = 0; ks < 4; ++ks) {
    const float* xr = x + (size_t)arow * 128 + ks * 32 + g * 8;
    float4 v0 = *(const float4*)xr;
    float4 v1 = *(const float4*)(xr + 4);
    uint4 au;
    au.x = cvt_pk_bf16(v0.x, v0.y);
    au.y = cvt_pk_bf16(v0.z, v0.w);
    au.z = cvt_pk_bf16(v1.x, v1.y);
    au.w = cvt_pk_bf16(v1.z, v1.w);
    short8 af = __builtin_bit_cast(short8, au);
#pragma unroll
    for (int nt = 0; nt < 8; ++nt) {
      short8 bf = *(const short8*)(wf + ((size_t)(ks * 8 + nt) * 64 + lane) * 8);
      acc[nt] = __builtin_amdgcn_mfma_f32_16x16x32_bf16(af, bf, acc[nt], 0, 0, 0);
    }
  }

  const int odd = c & 1;
#pragma unroll
  for (int r = 0; r < 4; ++r) {
    const int row = r0 + g * 4 + r;
    if (row >= n) continue;
    unsigned int* dp = Wxb + (size_t)row * 64;
#pragma unroll
    for (int ntp = 0; ntp < 4; ++ntp) {
      float ve = acc[ntp][r], vo = acc[ntp + 4][r];
      float vex = __shfl_xor(ve, 1, 64);
      float vox = __shfl_xor(vo, 1, 64);
      const int nt = odd ? ntp + 4 : ntp;
      dp[nt * 8 + (c >> 1)] = cvt_pk_bf16(odd ? vox : ve, odd ? vo : vex);
    }
  }

  float aiv[8], ajv[8];
#pragma unroll
  for (int nt = 0; nt < 8; ++nt) {
    const int hh = nt >> 1, ch = (nt & 1) * 16 + c;
    aiv[nt] = attn[hh * 64 + ch];
    ajv[nt] = attn[hh * 64 + 32 + ch];
  }
#pragma unroll
  for (int r = 0; r < 4; ++r) {
    float pih[4], pjh[4];
#pragma unroll
    for (int h = 0; h < 4; ++h) {
      pih[h] = acc[2 * h][r] * aiv[2 * h] + acc[2 * h + 1][r] * aiv[2 * h + 1];
      pjh[h] = acc[2 * h][r] * ajv[2 * h] + acc[2 * h + 1][r] * ajv[2 * h + 1];
    }
#pragma unroll
    for (int m = 1; m < 16; m <<= 1) {
#pragma unroll
      for (int h = 0; h < 4; ++h) {
        pih[h] += __shfl_xor(pih[h], m, 64);
        pjh[h] += __shfl_xor(pjh[h], m, 64);
      }
    }
    const int row = r0 + g * 4 + r;
    if (c == 0 && row < n) {
#pragma unroll
      for (int h = 0; h < 4; ++h) {
        s_i[(size_t)row * 4 + h] = pih[h];
        s_j[(size_t)row * 4 + h] = pjh[h];
      }
    }
  }
}

// ---------------------------------------------------------------- bin1
__global__ void k_bin1(const int* __restrict__ edges, const int* __restrict__ gcnt,
                       int* __restrict__ gcur, unsigned int* __restrict__ tmp, int E) {
  __shared__ int ws[4];
  __shared__ int bst_s[256];
  __shared__ int lcnt[256];
  __shared__ int lbase[256];
  const int t = threadIdx.x;
  const int excl = blk_excl_scan(gcnt[t], ws);
  bst_s[t] = excl;
  lcnt[t] = 0;
  __syncthreads();
  const int base = blockIdx.x * (256 * BIN_VPT);
  unsigned int pv[BIN_VPT];
  int rk[BIN_VPT];
#pragma unroll
  for (int j = 0; j < BIN_VPT; ++j) {
    int e = base + j * 256 + t;
    if (e < E) {
      unsigned int s = (unsigned int)edges[e];
      unsigned int d = (unsigned int)edges[E + e];
      pv[j] = s | (d << 16);
      rk[j] = atomicAdd(&lcnt[d >> 8], 1);
    } else {
      pv[j] = 0u;
      rk[j] = -1;
    }
  }
  __syncthreads();
  const int c = lcnt[t];
  lbase[t] = bst_s[t] + (c ? atomicAdd(&gcur[t], c) : 0);
  __syncthreads();
#pragma unroll
  for (int j = 0; j < BIN_VPT; ++j) {
    if (rk[j] >= 0) {
      const int b = pv[j] >> 24;  // dst >> 8
      tmp[lbase[b] + rk[j]] = pv[j];
    }
  }
}

// ---------------------------------------------------------------- bin2
// one block per bucket: node counts -> scan (offs/cnts) -> placement.
// Placement also computes per-edge softmax numerators pexp[e][0..3].
__global__ void k_bin2(const unsigned int* __restrict__ tmp, const int* __restrict__ gcnt,
                       const float* __restrict__ s_i, const float* __restrict__ s_j,
                       int* __restrict__ csr, float* __restrict__ pexp,
                       int* __restrict__ offs, int* __restrict__ cnts, int n) {
  __shared__ int ws[4];
  __shared__ int bst_s[256];
  __shared__ int nc[256];
  __shared__ float sjs[256][4];
  const int b = blockIdx.x;
  const int t = threadIdx.x;
  bst_s[t] = blk_excl_scan(gcnt[t], ws);
  nc[t] = 0;
  {
    const int node = b * 256 + t;
    float4 sj = make_float4(0.f, 0.f, 0.f, 0.f);
    if (node < n) sj = *(const float4*)(s_j + (size_t)node * 4);
    *(float4*)&sjs[t][0] = sj;
  }
  __syncthreads();
  const int base = bst_s[b], cnt = gcnt[b];
  for (int i = t; i < cnt; i += 256)
    atomicAdd(&nc[(tmp[base + i] >> 16) & 255], 1);
  __syncthreads();
  const int node = b * 256 + t;
  const int c = nc[t];
  if (node < n) cnts[node] = c;
  __syncthreads();           // blk_excl_scan reuses ws; ensure count phase done
  const int excl = blk_excl_scan(c, ws);
  if (node < n) offs[node] = base + excl;
  __syncthreads();           // everyone done reading nc from count phase
  nc[t] = excl;              // becomes local cursor
  __syncthreads();
  for (int i = t; i < cnt; i += 256) {
    unsigned int v = tmp[base + i];
    const int srcv = (int)(v & 0xFFFFu);
    const int loc = (v >> 16) & 255;
    int pos = atomicAdd(&nc[loc], 1);
    const float4 si = *(const float4*)(s_i + (size_t)srcv * 4);
    const float4 sj = *(const float4*)&sjs[loc][0];
    float4 p;
    p.x = __expf(lrelu(si.x + sj.x));
    p.y = __expf(lrelu(si.y + sj.y));
    p.z = __expf(lrelu(si.z + sj.z));
    p.w = __expf(lrelu(si.w + sj.w));
    csr[base + pos] = srcv;
    *(float4*)(pexp + (size_t)(base + pos) * 4) = p;
  }
}

// ---------------------------------------------------------------- agg + GEMM2
// 4 waves/block (256 thr), 16 nodes/block, 4 consecutive nodes per wave.
#define AGG_EDGE(e)                                                     \
  {                                                                     \
    int s_ = lsrc[wv][e];                                               \
    float p_ = lp[wv][e][h];                                            \
    unsigned int w_ = Wxb[(unsigned)(s_ << 6) | (unsigned)lane];        \
    acc.x += p_ * bflo(w_);                                             \
    acc.y += p_ * bfhi(w_);                                             \
    smh += p_;                                                          \
  }

__global__ void k_aggm(const unsigned int* __restrict__ Wxb,
                       const int* __restrict__ offs, const int* __restrict__ cnts,
                       const int* __restrict__ csr_src, const float* __restrict__ pexp,
                       const unsigned short* __restrict__ owf, const float* __restrict__ ob,
                       float* __restrict__ out, int n) {
  __shared__ unsigned int aTile[16][65];
  __shared__ int   lsrc[4][64];
  __shared__ float lp[4][64][4];
  const int lane = threadIdx.x & 63;
  const int wv = threadIdx.x >> 6;
  const int nd0 = blockIdx.x * 16;
  const int nd0w = nd0 + wv * 4;       // first of this wave's 4 nodes
  const int h = lane >> 4;

  // per-node degrees in lanes 0..3; boundaries b0<b1<b2 within the wave span
  int degv = 0;
  if (lane < 4 && nd0w + lane < n) degv = cnts[nd0w + lane];
  const int wbase = (nd0w < n) ? offs[nd0w] : 0;
  const int d0 = __shfl(degv, 0, 64), d1 = __shfl(degv, 1, 64);
  const int d2 = __shfl(degv, 2, 64), d3 = __shfl(degv, 3, 64);
  const int b0 = d0, b1 = d0 + d1, b2 = b1 + d2;
  const int tot = b2 + d3;

  int cur = 0;
  int rem = d0;
  float2 acc = make_float2(0.f, 0.f);
  float smh = 0.f;

  // leading zero-degree nodes
  while (cur < 4 && rem == 0) {
    if (nd0w + cur < n) aTile[(wv << 2) + cur][lane] = 0u;  // agg row = 0
    ++cur;
    rem = (cur == 1) ? d1 : (cur == 2) ? d2 : (cur == 3) ? d3 : 0;
  }

  for (int c0 = 0; c0 < tot; c0 += 64) {
    const int m = min(64, tot - c0);
    if (lane < m) {  // two coalesced loads -> LDS (no gather, no exp)
      lsrc[wv][lane] = csr_src[wbase + c0 + lane];
      *(float4*)&lp[wv][lane][0] = *(const float4*)(pexp + (size_t)(wbase + c0 + lane) * 4);
    }
    asm volatile("s_waitcnt lgkmcnt(0)" ::: "memory");  // same-wave LDS RAW
    int k = 0;
    while (k < m) {
      const int take = min(m - k, rem);
      int e = k;
      const int end = k + take;
      for (; e + 8 <= end; e += 8) {  // 8 independent 256B row loads in flight
        AGG_EDGE(e + 0) AGG_EDGE(e + 1) AGG_EDGE(e + 2) AGG_EDGE(e + 3)
        AGG_EDGE(e + 4) AGG_EDGE(e + 5) AGG_EDGE(e + 6) AGG_EDGE(e + 7)
      }
      for (; e + 4 <= end; e += 4) {
        AGG_EDGE(e + 0) AGG_EDGE(e + 1) AGG_EDGE(e + 2) AGG_EDGE(e + 3)
      }
      for (; e < end; ++e) AGG_EDGE(e)
      k += take;
      rem -= take;
      while (rem == 0 && cur < 4) {  // finalize node(s); skip zero-deg
        const float inv = 1.f / (smh + 1e-16f);
        if (nd0w + cur < n)
          aTile[(wv << 2) + cur][lane] = cvt_pk_bf16(acc.x * inv, acc.y * inv);
        ++cur;
        acc.x = 0.f; acc.y = 0.f; smh = 0.f;
        rem = (cur == 1) ? d1 : (cur == 2) ? d2 : (cur == 3) ? d3 : 0;
      }
      if (cur >= 4) break;
    }
  }
  __syncthreads();

  // ---- phase 2: out-GEMM on the 16-row tile; each wave does 2 col-tiles
  const int g = lane >> 4, c = lane & 15;
#pragma unroll
  for (int t2 = 0; t2 < 2; ++t2) {
    const int nt = wv + t2 * 4;
    f32x4 o = (f32x4){0.f, 0.f, 0.f, 0.f};
#pragma unroll
    for (int ks = 0; ks < 4; ++ks) {
      uint4 au = *(const uint4*)&aTile[c][ks * 16 + g * 4];  // A row = lane&15
      short8 af = __builtin_bit_cast(short8, au);
      short8 bf = *(const short8*)(owf + ((size_t)(ks * 8 + nt) * 64 + lane) * 8);
      o = __builtin_amdgcn_mfma_f32_16x16x32_bf16(af, bf, o, 0, 0, 0);
    }
#pragma unroll
    for (int r = 0; r < 4; ++r) {
      const int row = nd0 + g * 4 + r;   // D row = (lane>>4)*4 + r
      if (row < n) {
        float v = o[r] + ob[nt * 16 + c];
        v = v > 0.f ? v : expm1f(v);
        out[(size_t)row * 128 + nt * 16 + c] = v;
      }
    }
  }
}

// ---------------------------------------------------------------- launch
extern "C" void kernel_launch(void* const* d_in, const int* in_sizes, int n_in,
                              void* d_out, int out_size, void* d_ws, size_t ws_size,
                              hipStream_t stream) {
  const float* x    = (const float*)d_in[0];
  const int*   edges = (const int*)d_in[1];   // [2,E] (src row then dst row)
  const float* W    = (const float*)d_in[2];
  const float* attn = (const float*)d_in[3];
  const float* ow   = (const float*)d_in[4];
  const float* ob   = (const float*)d_in[5];
  const int n = in_sizes[0] / 128;            // 50000 (< 65536: u32 edge pack)
  const int E = in_sizes[1] / 2;
  float* out = (float*)d_out;

  char* wp = (char*)d_ws;
  auto alloc = [&](size_t bytes) {
    char* p = wp;
    wp += (bytes + 255) & ~(size_t)255;
    return p;
  };
  unsigned short* wf  = (unsigned short*)alloc(2048 * 8 * 2);
  unsigned short* owf = (unsigned short*)alloc(2048 * 8 * 2);
  unsigned int*   Wxb = (unsigned int*)alloc((size_t)n * 64 * 4);
  float* s_i    = (float*)alloc((size_t)n * 4 * 4);
  float* s_j    = (float*)alloc((size_t)n * 4 * 4);
  int*   gcnt   = (int*)alloc(256 * 4);
  int*   gcur   = (int*)alloc(256 * 4);
  int*   offs   = (int*)alloc((size_t)n * 4);
  int*   cnts   = (int*)alloc((size_t)n * 4);
  unsigned int* tmp = (unsigned int*)alloc((size_t)E * 4);
  int*   csr    = (int*)alloc((size_t)E * 4);
  float* pexp   = (float*)alloc((size_t)E * 4 * 4);

  dim3 blk(256);
  const int NB = (n + 255) / 256;                            // node buckets (196)
  const int EB = (E + 256 * BIN_VPT - 1) / (256 * BIN_VPT);  // edge blocks (196)
  const int strips = (n + 15) / 16;
  const int gemmBlocks = (strips + 3) / 4;

  k_setup<<<16, blk, 0, stream>>>(W, ow, wf, owf, gcnt, gcur);
  k_gemm1b<<<gemmBlocks + EB, blk, 0, stream>>>(x, wf, attn, Wxb, s_i, s_j, n,
                                                edges + E, gcnt, E, gemmBlocks);
  k_bin1<<<EB, blk, 0, stream>>>(edges, gcnt, gcur, tmp, E);
  k_bin2<<<NB, blk, 0, stream>>>(tmp, gcnt, s_i, s_j, csr, pexp, offs, cnts, n);
  k_aggm<<<(n + 15) / 16, blk, 0, stream>>>(Wxb, offs, cnts, csr, pexp,
                                            owf, ob, out, n);
}

// Round 9
// 97.156 us; speedup vs baseline: 1.0535x; 1.0535x over previous
//
#include <hip/hip_runtime.h>
#include <math.h>

// GAT layer: N=50000 nodes, E=800000 edges, D_IN=D_OUT=128, H=4, D_H=32
//
// 5-dispatch pipeline:
//   k_setup  : pack W / out_w into bf16 MFMA B-fragments + zero gcnt/gcur
//   k_gemm1b : Wx(bf16) = x @ W via MFMA + fused attention scores s_i/s_j;
//              trailing blocks do the dst-bucket histogram (bucket = dst>>8)
//   k_bin1   : block-local counting sort -> bucket-contiguous tmp
//   k_bin2   : one block per bucket: node counts + scan (emits offs/cnts) +
//              placement — all scatter block-private
//   k_aggm   : 4 waves/block, 4 consecutive nodes per wave. Staging: 64 edges
//              lane-parallel (csr + s_i gather + exp) -> LDS. Consumer: TWO
//              edges per instruction stream (lanes 0-31 edge e, lanes 32-63
//              edge e+1; dwordx2 = 4 bf16 cols/lane) — halves per-edge issue
//              cost and load-instruction count. Node finalize merges the two
//              half-wave partials via shfl_xor(32). Phase 2: output GEMM
//              (MFMA) + bias + ELU straight from the LDS tile.

typedef __attribute__((ext_vector_type(8))) short short8;
typedef __attribute__((ext_vector_type(4))) float f32x4;

#define BIN_VPT 16          // edges per thread; 4096 edges per 256-thread block

__device__ __forceinline__ float lrelu(float v) { return v >= 0.f ? v : 0.2f * v; }

__device__ __forceinline__ unsigned short f2bf(float f) {  // RNE f32 -> bf16
  unsigned int u = __float_as_uint(f);
  u += 0x7FFFu + ((u >> 16) & 1u);
  return (unsigned short)(u >> 16);
}
// HW packed RNE convert: dst = bf16(lo) | bf16(hi)<<16
__device__ __forceinline__ unsigned int cvt_pk_bf16(float lo, float hi) {
  unsigned int r;
  asm("v_cvt_pk_bf16_f32 %0, %1, %2" : "=v"(r) : "v"(lo), "v"(hi));
  return r;
}
__device__ __forceinline__ float bflo(unsigned int w) { return __uint_as_float(w << 16); }
__device__ __forceinline__ float bfhi(unsigned int w) { return __uint_as_float(w & 0xFFFF0000u); }

// 256-thread exclusive scan helper (value v per thread -> returns excl; ws[4] LDS)
__device__ __forceinline__ int blk_excl_scan(int v, int* ws) {
  const int t = threadIdx.x, lane = t & 63, wv = t >> 6;
  int incl = v;
#pragma unroll
  for (int m = 1; m < 64; m <<= 1) {
    int x = __shfl_up(incl, m, 64);
    if (lane >= m) incl += x;
  }
  if (lane == 63) ws[wv] = incl;
  __syncthreads();
  int woff = 0;
  for (int p = 0; p < wv; ++p) woff += ws[p];
  return woff + incl - v;
}

// ---------------------------------------------------------------- setup
__global__ void k_setup(const float* __restrict__ W, const float* __restrict__ ow,
                        unsigned short* __restrict__ wf, unsigned short* __restrict__ owf,
                        int* __restrict__ gcnt, int* __restrict__ gcur) {
  const int t = blockIdx.x * 256 + threadIdx.x;
  if (blockIdx.x == 0) gcnt[threadIdx.x] = 0;
  if (blockIdx.x == 1) gcur[threadIdx.x] = 0;
  const int which = t >> 11;           // 0: W, 1: out_w
  const int tt = t & 2047;
  const float* M = which ? ow : W;
  unsigned short* F = which ? owf : wf;
  const int lane = tt & 63;
  const int nt = (tt >> 6) & 7;
  const int ks = tt >> 9;
  const int k0 = ks * 32 + (lane >> 4) * 8;
  const int col = nt * 16 + (lane & 15);
  short8 v;
#pragma unroll
  for (int j = 0; j < 8; ++j) v[j] = (short)f2bf(M[(k0 + j) * 128 + col]);
  *(short8*)(F + (size_t)tt * 8) = v;
}

// ---------------------------------------------------------------- GEMM1 + hist
__global__ void k_gemm1b(const float* __restrict__ x, const unsigned short* __restrict__ wf,
                         const float* __restrict__ attn, unsigned int* __restrict__ Wxb,
                         float* __restrict__ s_i, float* __restrict__ s_j, int n,
                         const int* __restrict__ dst, int* __restrict__ gcnt, int E,
                         int gemmBlocks) {
  __shared__ int lc[256];
  if (blockIdx.x >= gemmBlocks) {  // ---- histogram part
    const int bb = blockIdx.x - gemmBlocks;
    lc[threadIdx.x] = 0;
    __syncthreads();
    const int base = bb * (256 * BIN_VPT);
#pragma unroll
    for (int j = 0; j < BIN_VPT; ++j) {
      int e = base + j * 256 + threadIdx.x;
      if (e < E) atomicAdd(&lc[((unsigned int)dst[e]) >> 8], 1);
    }
    __syncthreads();
    int c = lc[threadIdx.x];
    if (c) atomicAdd(&gcnt[threadIdx.x], c);
    return;
  }

  // ---- GEMM part: one wave = 16-row strip, acc[nt] covers cols nt*16..+15
  const int lane = threadIdx.x & 63;
  const int gw = blockIdx.x * (blockDim.x >> 6) + (threadIdx.x >> 6);
  const int r0 = gw * 16;
  if (r0 >= n) return;
  const int g = lane >> 4, c = lane & 15;

  f32x4 acc[8];
#pragma unroll
  for (int nt = 0; nt < 8; ++nt) acc[nt] = (f32x4){0.f, 0.f, 0.f, 0.f};

  const int arow = min(r0 + c, n - 1);
#pragma unroll
  for (int ks = 0; ks < 4; ++ks) {
    const float* xr = x + (size_t)arow * 128 + ks * 32 + g * 8;
    float4 v0 = *(const float4*)xr;
    float4 v1 = *(const float4*)(xr + 4);
    uint4 au;
    au.x = cvt_pk_bf16(v0.x, v0.y);
    au.y = cvt_pk_bf16(v0.z, v0.w);
    au.z = cvt_pk_bf16(v1.x, v1.y);
    au.w = cvt_pk_bf16(v1.z, v1.w);
    short8 af = __builtin_bit_cast(short8, au);
#pragma unroll
    for (int nt = 0; nt < 8; ++nt) {
      short8 bf = *(const short8*)(wf + ((size_t)(ks * 8 + nt) * 64 + lane) * 8);
      acc[nt] = __builtin_amdgcn_mfma_f32_16x16x32_bf16(af, bf, acc[nt], 0, 0, 0);
    }
  }

  const int odd = c & 1;
#pragma unroll
  for (int r = 0; r < 4; ++r) {
    const int row = r0 + g * 4 + r;
    if (row >= n) continue;
    unsigned int* dp = Wxb + (size_t)row * 64;
#pragma unroll
    for (int ntp = 0; ntp < 4; ++ntp) {
      float ve = acc[ntp][r], vo = acc[ntp + 4][r];
      float vex = __shfl_xor(ve, 1, 64);
      float vox = __shfl_xor(vo, 1, 64);
      const int nt = odd ? ntp + 4 : ntp;
      dp[nt * 8 + (c >> 1)] = cvt_pk_bf16(odd ? vox : ve, odd ? vo : vex);
    }
  }

  float aiv[8], ajv[8];
#pragma unroll
  for (int nt = 0; nt < 8; ++nt) {
    const int hh = nt >> 1, ch = (nt & 1) * 16 + c;
    aiv[nt] = attn[hh * 64 + ch];
    ajv[nt] = attn[hh * 64 + 32 + ch];
  }
#pragma unroll
  for (int r = 0; r < 4; ++r) {
    float pih[4], pjh[4];
#pragma unroll
    for (int h = 0; h < 4; ++h) {
      pih[h] = acc[2 * h][r] * aiv[2 * h] + acc[2 * h + 1][r] * aiv[2 * h + 1];
      pjh[h] = acc[2 * h][r] * ajv[2 * h] + acc[2 * h + 1][r] * ajv[2 * h + 1];
    }
#pragma unroll
    for (int m = 1; m < 16; m <<= 1) {
#pragma unroll
      for (int h = 0; h < 4; ++h) {
        pih[h] += __shfl_xor(pih[h], m, 64);
        pjh[h] += __shfl_xor(pjh[h], m, 64);
      }
    }
    const int row = r0 + g * 4 + r;
    if (c == 0 && row < n) {
#pragma unroll
      for (int h = 0; h < 4; ++h) {
        s_i[(size_t)row * 4 + h] = pih[h];
        s_j[(size_t)row * 4 + h] = pjh[h];
      }
    }
  }
}

// ---------------------------------------------------------------- bin1
__global__ void k_bin1(const int* __restrict__ edges, const int* __restrict__ gcnt,
                       int* __restrict__ gcur, unsigned int* __restrict__ tmp, int E) {
  __shared__ int ws[4];
  __shared__ int bst_s[256];
  __shared__ int lcnt[256];
  __shared__ int lbase[256];
  const int t = threadIdx.x;
  const int excl = blk_excl_scan(gcnt[t], ws);
  bst_s[t] = excl;
  lcnt[t] = 0;
  __syncthreads();
  const int base = blockIdx.x * (256 * BIN_VPT);
  unsigned int pv[BIN_VPT];
  int rk[BIN_VPT];
#pragma unroll
  for (int j = 0; j < BIN_VPT; ++j) {
    int e = base + j * 256 + t;
    if (e < E) {
      unsigned int s = (unsigned int)edges[e];
      unsigned int d = (unsigned int)edges[E + e];
      pv[j] = s | (d << 16);
      rk[j] = atomicAdd(&lcnt[d >> 8], 1);
    } else {
      pv[j] = 0u;
      rk[j] = -1;
    }
  }
  __syncthreads();
  const int c = lcnt[t];
  lbase[t] = bst_s[t] + (c ? atomicAdd(&gcur[t], c) : 0);
  __syncthreads();
#pragma unroll
  for (int j = 0; j < BIN_VPT; ++j) {
    if (rk[j] >= 0) {
      const int b = pv[j] >> 24;  // dst >> 8
      tmp[lbase[b] + rk[j]] = pv[j];
    }
  }
}

// ---------------------------------------------------------------- bin2
__global__ void k_bin2(const unsigned int* __restrict__ tmp, const int* __restrict__ gcnt,
                       int* __restrict__ csr, int* __restrict__ offs,
                       int* __restrict__ cnts, int n) {
  __shared__ int ws[4];
  __shared__ int bst_s[256];
  __shared__ int nc[256];
  const int b = blockIdx.x;
  const int t = threadIdx.x;
  bst_s[t] = blk_excl_scan(gcnt[t], ws);
  nc[t] = 0;
  __syncthreads();
  const int base = bst_s[b], cnt = gcnt[b];
  for (int i = t; i < cnt; i += 256)
    atomicAdd(&nc[(tmp[base + i] >> 16) & 255], 1);
  __syncthreads();
  const int node = b * 256 + t;
  const int c = nc[t];
  if (node < n) cnts[node] = c;
  __syncthreads();           // blk_excl_scan reuses ws; ensure count phase done
  const int excl = blk_excl_scan(c, ws);
  if (node < n) offs[node] = base + excl;
  __syncthreads();           // everyone done reading nc from count phase
  nc[t] = excl;              // becomes local cursor
  __syncthreads();
  for (int i = t; i < cnt; i += 256) {
    unsigned int v = tmp[base + i];
    int pos = atomicAdd(&nc[(v >> 16) & 255], 1);
    csr[base + pos] = (int)(v & 0xFFFFu);
  }
}

// ---------------------------------------------------------------- agg + GEMM2
// 4 waves/block (256 thr), 16 nodes/block, 4 consecutive nodes per wave.
// Consumer: 2 edges per instruction stream (half-wave split, dwordx2 loads).
#define AGG_PAIR(e)                                                       \
  {                                                                       \
    const int eA_ = (e) + half;                                           \
    const int s_ = lsrc[wv][eA_];                                         \
    const float p_ = lp[wv][eA_][hq];                                     \
    uint2 w_ = *(const uint2*)(WxbL + ((size_t)s_ << 6));                 \
    a0 += p_ * bflo(w_.x); a1 += p_ * bfhi(w_.x);                         \
    a2 += p_ * bflo(w_.y); a3 += p_ * bfhi(w_.y);                         \
    smh += p_;                                                            \
  }
#define AGG_SINGLE(e)                                                     \
  {                                                                       \
    const int s_ = lsrc[wv][e];                                           \
    const float p_ = half ? 0.f : lp[wv][e][hq];                          \
    uint2 w_ = *(const uint2*)(WxbL + ((size_t)s_ << 6));                 \
    a0 += p_ * bflo(w_.x); a1 += p_ * bfhi(w_.x);                         \
    a2 += p_ * bflo(w_.y); a3 += p_ * bfhi(w_.y);                         \
    smh += p_;                                                            \
  }

__global__ void k_aggm(const unsigned int* __restrict__ Wxb, const float* __restrict__ s_i,
                       const float* __restrict__ s_j, const int* __restrict__ offs,
                       const int* __restrict__ cnts, const int* __restrict__ csr_src,
                       const unsigned short* __restrict__ owf, const float* __restrict__ ob,
                       float* __restrict__ out, int n) {
  __shared__ unsigned int aTile[16][65];
  __shared__ int   lsrc[4][64];
  __shared__ float lp[4][64][4];
  const int lane = threadIdx.x & 63;
  const int wv = threadIdx.x >> 6;
  const int nd0 = blockIdx.x * 16;
  const int nd0w = nd0 + wv * 4;       // first of this wave's 4 nodes
  const int h = lane >> 4;             // staging head (per staged edge)
  const int half = lane >> 5;          // 0: edge e, 1: edge e+1
  const int cq = lane & 31;            // u32-pair column (4 bf16 cols)
  const int hq = cq >> 3;              // consumer head for this lane's cols
  const unsigned int* WxbL = Wxb + (cq << 1);

  // per-node degrees in lanes 0..3; boundaries within the wave span
  int degv = 0;
  if (lane < 4 && nd0w + lane < n) degv = cnts[nd0w + lane];
  const int wbase = (nd0w < n) ? offs[nd0w] : 0;
  const int d0 = __shfl(degv, 0, 64), d1 = __shfl(degv, 1, 64);
  const int d2 = __shfl(degv, 2, 64), d3 = __shfl(degv, 3, 64);
  const int tot = d0 + d1 + d2 + d3;

  int cur = 0;
  int rem = d0;
  float a0 = 0.f, a1 = 0.f, a2 = 0.f, a3 = 0.f;
  float smh = 0.f;

  // leading zero-degree nodes
  while (cur < 4 && rem == 0) {
    if (nd0w + cur < n) aTile[(wv << 2) + cur][lane] = 0u;  // agg row = 0
    ++cur;
    rem = (cur == 1) ? d1 : (cur == 2) ? d2 : (cur == 3) ? d3 : 0;
  }

  for (int c0 = 0; c0 < tot; c0 += 64) {
    const int m = min(64, tot - c0);
    if (lane < m) {  // stage: csr + s_i gather + exp -> LDS
      const int src = csr_src[wbase + c0 + lane];
      // node of this staged edge (position vs boundaries)
      const int pos = c0 + lane;
      const int nl = (pos >= d0) + (pos >= d0 + d1) + (pos >= d0 + d1 + d2);
      const float4 sj = *(const float4*)(s_j + (size_t)(nd0w + nl) * 4);
      const float4 si = *(const float4*)(s_i + (size_t)src * 4);
      float4 p;
      p.x = __expf(lrelu(si.x + sj.x));
      p.y = __expf(lrelu(si.y + sj.y));
      p.z = __expf(lrelu(si.z + sj.z));
      p.w = __expf(lrelu(si.w + sj.w));
      lsrc[wv][lane] = src;
      *(float4*)&lp[wv][lane][0] = p;
    }
    asm volatile("s_waitcnt lgkmcnt(0)" ::: "memory");  // same-wave LDS RAW
    int k = 0;
    while (k < m) {
      const int take = min(m - k, rem);
      const int npair2 = take & ~1;    // even count processed as pairs
      int e = k;
      const int endp = k + npair2;
      for (; e + 8 <= endp; e += 8) {  // 4 pair-steps = 8 edges, 4 loads
        AGG_PAIR(e) AGG_PAIR(e + 2) AGG_PAIR(e + 4) AGG_PAIR(e + 6)
      }
      for (; e < endp; e += 2) AGG_PAIR(e)
      if (take & 1) AGG_SINGLE(k + npair2)
      k += take;
      rem -= take;
      while (rem == 0 && cur < 4) {  // finalize node(s); skip zero-deg
        float f0 = a0 + __shfl_xor(a0, 32, 64);
        float f1 = a1 + __shfl_xor(a1, 32, 64);
        float f2 = a2 + __shfl_xor(a2, 32, 64);
        float f3 = a3 + __shfl_xor(a3, 32, 64);
        float st = smh + __shfl_xor(smh, 32, 64);
        const float inv = 1.f / (st + 1e-16f);
        if (half == 0 && nd0w + cur < n) {
          aTile[(wv << 2) + cur][(cq << 1) + 0] = cvt_pk_bf16(f0 * inv, f1 * inv);
          aTile[(wv << 2) + cur][(cq << 1) + 1] = cvt_pk_bf16(f2 * inv, f3 * inv);
        }
        ++cur;
        a0 = a1 = a2 = a3 = 0.f; smh = 0.f;
        rem = (cur == 1) ? d1 : (cur == 2) ? d2 : (cur == 3) ? d3 : 0;
      }
      if (cur >= 4) break;
    }
  }
  __syncthreads();

  // ---- phase 2: out-GEMM on the 16-row tile; each wave does 2 col-tiles
  const int g = lane >> 4, c = lane & 15;
#pragma unroll
  for (int t2 = 0; t2 < 2; ++t2) {
    const int nt = wv + t2 * 4;
    f32x4 o = (f32x4){0.f, 0.f, 0.f, 0.f};
#pragma unroll
    for (int ks = 0; ks < 4; ++ks) {
      uint4 au = *(const uint4*)&aTile[c][ks * 16 + g * 4];  // A row = lane&15
      short8 af = __builtin_bit_cast(short8, au);
      short8 bf = *(const short8*)(owf + ((size_t)(ks * 8 + nt) * 64 + lane) * 8);
      o = __builtin_amdgcn_mfma_f32_16x16x32_bf16(af, bf, o, 0, 0, 0);
    }
#pragma unroll
    for (int r = 0; r < 4; ++r) {
      const int row = nd0 + g * 4 + r;   // D row = (lane>>4)*4 + r
      if (row < n) {
        float v = o[r] + ob[nt * 16 + c];
        v = v > 0.f ? v : expm1f(v);
        out[(size_t)row * 128 + nt * 16 + c] = v;
      }
    }
  }
}

// ---------------------------------------------------------------- launch
extern "C" void kernel_launch(void* const* d_in, const int* in_sizes, int n_in,
                              void* d_out, int out_size, void* d_ws, size_t ws_size,
                              hipStream_t stream) {
  const float* x    = (const float*)d_in[0];
  const int*   edges = (const int*)d_in[1];   // [2,E] (src row then dst row)
  const float* W    = (const float*)d_in[2];
  const float* attn = (const float*)d_in[3];
  const float* ow   = (const float*)d_in[4];
  const float* ob   = (const float*)d_in[5];
  const int n = in_sizes[0] / 128;            // 50000 (< 65536: u32 edge pack)
  const int E = in_sizes[1] / 2;
  float* out = (float*)d_out;

  char* wp = (char*)d_ws;
  auto alloc = [&](size_t bytes) {
    char* p = wp;
    wp += (bytes + 255) & ~(size_t)255;
    return p;
  };
  unsigned short* wf  = (unsigned short*)alloc(2048 * 8 * 2);
  unsigned short* owf = (unsigned short*)alloc(2048 * 8 * 2);
  unsigned int*   Wxb = (unsigned int*)alloc((size_t)n * 64 * 4);
  float* s_i    = (float*)alloc((size_t)n * 4 * 4);
  float* s_j    = (float*)alloc((size_t)n * 4 * 4);
  int*   gcnt   = (int*)alloc(256 * 4);
  int*   gcur   = (int*)alloc(256 * 4);
  int*   offs   = (int*)alloc((size_t)n * 4);
  int*   cnts   = (int*)alloc((size_t)n * 4);
  unsigned int* tmp = (unsigned int*)alloc((size_t)E * 4);
  int*   csr    = (int*)alloc((size_t)E * 4);

  dim3 blk(256);
  const int NB = (n + 255) / 256;                            // node buckets (196)
  const int EB = (E + 256 * BIN_VPT - 1) / (256 * BIN_VPT);  // edge blocks (196)
  const int strips = (n + 15) / 16;
  const int gemmBlocks = (strips + 3) / 4;

  k_setup<<<16, blk, 0, stream>>>(W, ow, wf, owf, gcnt, gcur);
  k_gemm1b<<<gemmBlocks + EB, blk, 0, stream>>>(x, wf, attn, Wxb, s_i, s_j, n,
                                                edges + E, gcnt, E, gemmBlocks);
  k_bin1<<<EB, blk, 0, stream>>>(edges, gcnt, gcur, tmp, E);
  k_bin2<<<NB, blk, 0, stream>>>(tmp, gcnt, csr, offs, cnts, n);
  k_aggm<<<(n + 15) / 16, blk, 0, stream>>>(Wxb, s_i, s_j, offs, cnts, csr,
                                            owf, ob, out, n);
}